// Round 5
// baseline (374.991 us; speedup 1.0000x reference)
//
#include <hip/hip_runtime.h>
#include <cmath>

typedef unsigned short u16;
typedef __attribute__((ext_vector_type(8))) short bf16x8;
typedef __attribute__((ext_vector_type(4))) float f32x4;
typedef __attribute__((ext_vector_type(8))) unsigned short u16x8;

#define B_  32
#define N_  1024
#define L_  256
#define S_  8
#define DT_ 512
#define BAND_ 16

__device__ __forceinline__ u16 f2bf(float f) {
  union { float f; unsigned u; } x; x.f = f;
  unsigned r = (x.u + 0x7fffu + ((x.u >> 16) & 1u)) >> 16;
  return (u16)r;
}
__device__ __forceinline__ float bf2f(u16 h) {
  union { unsigned u; float f; } x; x.u = ((unsigned)h) << 16;
  return x.f;
}

// ---------------------------------------------------------------------------
// f32 -> bf16 conversion (vectorized x4)
// ---------------------------------------------------------------------------
__global__ __launch_bounds__(256) void cvt_bf16(
    const float* __restrict__ in, u16* __restrict__ out, int n4) {
  int i = blockIdx.x * 256 + threadIdx.x;
  if (i < n4) {
    float4 v = ((const float4*)in)[i];
    ushort4 o;
    o.x = f2bf(v.x); o.y = f2bf(v.y); o.z = f2bf(v.z); o.w = f2bf(v.w);
    ((ushort4*)out)[i] = o;
  }
}

// ---------------------------------------------------------------------------
// All small weights in one launch. float4 counts:
// emb 131072 | wq 65536 | wk 65536 | wv 65536 | wv2t 65536 | pwk 65536
// ---------------------------------------------------------------------------
__global__ __launch_bounds__(256) void cvt_weights(
    const float* __restrict__ e, const float* __restrict__ q,
    const float* __restrict__ k, const float* __restrict__ v,
    const float* __restrict__ t, const float* __restrict__ pw,
    u16* __restrict__ eo, u16* __restrict__ qo, u16* __restrict__ kvo,
    u16* __restrict__ to, u16* __restrict__ po) {
  int i = blockIdx.x * 256 + threadIdx.x;
  const float* src; u16* dst; int soff, doff;
  if (i < 131072)      { src = e;  dst = eo;  soff = i;          doff = soff; }
  else if (i < 196608) { src = q;  dst = qo;  soff = i - 131072; doff = soff; }
  else if (i < 262144) { src = k;  dst = kvo; soff = i - 196608; doff = soff; }
  else if (i < 327680) { src = v;  dst = kvo; soff = i - 262144; doff = soff + 65536; }
  else if (i < 393216) { src = t;  dst = to;  soff = i - 327680; doff = soff; }
  else                 { src = pw; dst = po;  soff = i - 393216; doff = soff; }
  float4 vv = ((const float4*)src)[soff];
  ushort4 o;
  o.x = f2bf(vv.x); o.y = f2bf(vv.y); o.z = f2bf(vv.z); o.w = f2bf(vv.w);
  ((ushort4*)dst)[doff] = o;
}

// ---------------------------------------------------------------------------
// K1: per (b,l): gather emb rows, depthwise conv (k=3, SAME, cross-corr),
// silu, mean over s -> shm (bf16); meanE -> mbuf (f32)
// ---------------------------------------------------------------------------
__global__ __launch_bounds__(256) void text_front(
    const int* __restrict__ ids, const float* __restrict__ emb,
    const float* __restrict__ dwk, u16* __restrict__ shm,
    float* __restrict__ mbuf) {
  int bl = blockIdx.x;
  int tid = threadIdx.x;
  __shared__ int sid[S_];
  if (tid < S_) sid[tid] = ids[bl * S_ + tid];
  __syncthreads();
  for (int c = tid; c < DT_; c += 256) {
    float x[S_];
#pragma unroll
    for (int s = 0; s < S_; ++s) x[s] = emb[(size_t)sid[s] * DT_ + c];
    float k0 = dwk[c * 3 + 0], k1 = dwk[c * 3 + 1], k2 = dwk[c * 3 + 2];
    float me = 0.f, sh = 0.f;
#pragma unroll
    for (int s = 0; s < S_; ++s) {
      float xm = (s > 0) ? x[s - 1] : 0.0f;
      float xp = (s < S_ - 1) ? x[s + 1] : 0.0f;
      float h = k0 * xm + k1 * x[s] + k2 * xp;
      float si = h / (1.0f + expf(-h));  // silu
      me += x[s];
      sh += si;
    }
    shm[(size_t)bl * DT_ + c] = f2bf(sh * (1.0f / S_));
    mbuf[(size_t)bl * DT_ + c] = me * (1.0f / S_);
  }
}

// ---------------------------------------------------------------------------
// bf16 MFMA GEMM, 2-phase double-buffered + XCD-chunked swizzle.
// C[m][n] (+)= sum_k A[m][k]*B[n][k]; A:[M,K], B:[N,K] bf16 row-major.
// ---------------------------------------------------------------------------
template <bool ACC, bool WF32, bool WBF16>
__global__ __launch_bounds__(256) void gemm_mfma(
    const u16* __restrict__ A, const u16* __restrict__ B,
    float* __restrict__ C, u16* __restrict__ Cb, int M, int N, int K) {
  __shared__ u16 As[8192];  // [2][128][32]
  __shared__ u16 Bs[8192];
  const int tid = threadIdx.x;
  const int w = tid >> 6;
  const int lane = tid & 63;

  const int gx = gridDim.x;
  const int bid = blockIdx.y * gx + blockIdx.x;
  const int nwg = gx * gridDim.y;
  const int logical = (bid & 7) * (nwg >> 3) + (bid >> 3);
  const int bm = (logical / gx) << 7;
  const int bn = (logical % gx) << 7;
  const int wr = w >> 1, wc = w & 1;

  const int r0 = (w << 4) + (lane >> 2);
  const int kc = (lane & 3) << 3;
  const u16* Ag0 = A + (size_t)(bm + r0) * K + kc;
  const u16* Ag1 = Ag0 + (size_t)64 * K;
  const u16* Bg0 = B + (size_t)(bn + r0) * K + kc;
  const u16* Bg1 = Bg0 + (size_t)64 * K;

  int aoff[4], boff[4];
#pragma unroll
  for (int m = 0; m < 4; ++m)
    aoff[m] = (((wr << 6) + (m << 4) + (lane & 15)) << 5) + ((lane >> 4) << 3);
#pragma unroll
  for (int n = 0; n < 4; ++n)
    boff[n] = (((wc << 6) + (n << 4) + (lane & 15)) << 5) + ((lane >> 4) << 3);

  f32x4 acc[4][4];
#pragma unroll
  for (int m = 0; m < 4; ++m)
#pragma unroll
    for (int n = 0; n < 4; ++n) acc[m][n] = (f32x4){0.f, 0.f, 0.f, 0.f};

#define STAGE(buf, kt)                                                        \
  {                                                                           \
    u16* as_ = As + (buf) * 4096 + (w << 9);                                  \
    u16* bs_ = Bs + (buf) * 4096 + (w << 9);                                  \
    __builtin_amdgcn_global_load_lds(                                         \
        (const __attribute__((address_space(1))) void*)(Ag0 + (kt)),          \
        (__attribute__((address_space(3))) void*)as_, 16, 0, 0);              \
    __builtin_amdgcn_global_load_lds(                                         \
        (const __attribute__((address_space(1))) void*)(Ag1 + (kt)),          \
        (__attribute__((address_space(3))) void*)(as_ + 2048), 16, 0, 0);     \
    __builtin_amdgcn_global_load_lds(                                         \
        (const __attribute__((address_space(1))) void*)(Bg0 + (kt)),          \
        (__attribute__((address_space(3))) void*)bs_, 16, 0, 0);              \
    __builtin_amdgcn_global_load_lds(                                         \
        (const __attribute__((address_space(1))) void*)(Bg1 + (kt)),          \
        (__attribute__((address_space(3))) void*)(bs_ + 2048), 16, 0, 0);     \
  }

  const int nt = K >> 5;
  STAGE(0, 0);
  __syncthreads();
  int cur = 0;
  for (int t = 0; t < nt; ++t) {
    if (t + 1 < nt) STAGE(cur ^ 1, (t + 1) << 5);
    const u16* Ab = As + cur * 4096;
    const u16* Bb = Bs + cur * 4096;
    bf16x8 af[4], bfr[4];
#pragma unroll
    for (int m = 0; m < 4; ++m) af[m] = *(const bf16x8*)(Ab + aoff[m]);
#pragma unroll
    for (int n = 0; n < 4; ++n) bfr[n] = *(const bf16x8*)(Bb + boff[n]);
#pragma unroll
    for (int m = 0; m < 4; ++m)
#pragma unroll
      for (int n = 0; n < 4; ++n)
        acc[m][n] = __builtin_amdgcn_mfma_f32_16x16x32_bf16(
            af[m], bfr[n], acc[m][n], 0, 0, 0);
    __syncthreads();
    cur ^= 1;
  }
#undef STAGE

  const int rb = bm + (wr << 6) + ((lane >> 4) << 2);
  const int cb = bn + (wc << 6) + (lane & 15);
#pragma unroll
  for (int m = 0; m < 4; ++m) {
#pragma unroll
    for (int n = 0; n < 4; ++n) {
      int col = cb + (n << 4);
#pragma unroll
      for (int j = 0; j < 4; ++j) {
        size_t idx = (size_t)(rb + (m << 4) + j) * N + col;
        float v = acc[m][n][j];
        if (ACC) v += C[idx];
        if (WF32) C[idx] = v;
        if (WBF16) Cb[idx] = f2bf(v);
      }
    }
  }
}

// ---------------------------------------------------------------------------
// LayerNorm over DT=512 per row; writes bf16 q_txt
// ---------------------------------------------------------------------------
__global__ __launch_bounds__(256) void ln_kernel(
    const float* __restrict__ m, const float* __restrict__ g,
    const float* __restrict__ bta, u16* __restrict__ q) {
  int row = blockIdx.x;
  int tid = threadIdx.x;
  float v0 = m[(size_t)row * 512 + tid];
  float v1 = m[(size_t)row * 512 + 256 + tid];
  __shared__ float red[4], red2[4];
  float s = v0 + v1;
#pragma unroll
  for (int d = 32; d; d >>= 1) s += __shfl_xor(s, d);
  if ((tid & 63) == 0) red[tid >> 6] = s;
  __syncthreads();
  float mu = (red[0] + red[1] + red[2] + red[3]) * (1.0f / 512.0f);
  float d0 = v0 - mu, d1 = v1 - mu;
  float s2 = d0 * d0 + d1 * d1;
#pragma unroll
  for (int d = 32; d; d >>= 1) s2 += __shfl_xor(s2, d);
  if ((tid & 63) == 0) red2[tid >> 6] = s2;
  __syncthreads();
  float var = (red2[0] + red2[1] + red2[2] + red2[3]) * (1.0f / 512.0f);
  float r = rsqrtf(var + 1e-5f);
  q[(size_t)row * 512 + tid] = f2bf(d0 * r * g[tid] + bta[tid]);
  q[(size_t)row * 512 + 256 + tid] = f2bf(d1 * r * g[tid + 256] + bta[tid + 256]);
}

// ---------------------------------------------------------------------------
// Banded attention. Block = (b, 16 l), 512 threads = 8 waves x 2 l.
// Fixed 33-iteration unrolled band loops (row clamped, masked) for ILP.
// Q bf16. KV: [32768][1024] bf16, cols 0..511 = K, 512..1023 = V.
// av_s is wave-private (no block barriers).
// ---------------------------------------------------------------------------
__global__ __launch_bounds__(512, 4) void attn_kernel(
    const u16* __restrict__ Qb, const u16* __restrict__ KV,
    const float* __restrict__ alpha_p, float* __restrict__ A,
    u16* __restrict__ Fv) {
  __shared__ float av_s[16][64];
  // XCD-chunked bijective swizzle over 512 blocks (64 per XCD):
  const int bid = blockIdx.x;
  const int logical = (bid & 7) * 64 + (bid >> 3);
  const int b = logical >> 4, lg = logical & 15;
  const int tid = threadIdx.x;
  const int w = tid >> 6, lane = tid & 63;
  const float al = *alpha_p;

#pragma unroll
  for (int i = 0; i < 2; ++i) {
    const int wl = w * 2 + i;
    const int l = lg * 16 + wl;
    const int c = (1023 * l) / 255;
    // Q slice into registers (lane owns 8 channels)
    float qr[8];
    {
      const u16x8 qv = *(const u16x8*)(Qb + (size_t)(b * L_ + l) * 512 + lane * 8);
#pragma unroll
      for (int t = 0; t < 8; ++t) qr[t] = bf2f(qv[t]);
    }
    // QK^T over fixed 33 rows; lane j ends holding logit j
    float mylogit = 0.f;
#pragma unroll
    for (int j = 0; j < 33; ++j) {
      const int rcl = min(max(c - BAND_ + j, 0), N_ - 1);
      const u16x8 kv =
          *(const u16x8*)(KV + ((size_t)(b * N_ + rcl)) * 1024 + lane * 8);
      float s = 0.f;
#pragma unroll
      for (int t = 0; t < 8; ++t) s += bf2f(kv[t]) * qr[t];
#pragma unroll
      for (int d = 32; d; d >>= 1) s += __shfl_xor(s, d);
      mylogit = (lane == j) ? s : mylogit;
    }
    // register softmax across lanes (mask invalid rows / lanes >= 33)
    const int myrow = c - BAND_ + lane;
    const bool valid = (lane < 33) && (myrow >= 0) && (myrow < N_);
    float x = valid ? mylogit * 0.044194173824159216f +
                          al * ((float)(c - myrow) * (1.0f / 16.000001f))
                    : -INFINITY;
    float mx = x;
#pragma unroll
    for (int d = 32; d; d >>= 1) mx = fmaxf(mx, __shfl_xor(mx, d));
    float e = valid ? expf(x - mx) : 0.0f;
    float sm = e;
#pragma unroll
    for (int d = 32; d; d >>= 1) sm += __shfl_xor(sm, d);
    av_s[wl][lane] = valid ? (e / sm) : 0.0f;
    // A row (float4, zeros outside band); wave-local LDS gather
    const int lo = max(0, c - BAND_), hi = min(N_ - 1, c + BAND_);
    float* Arow = A + (size_t)(b * L_ + l) * N_;
#pragma unroll
    for (int p4 = 0; p4 < 4; ++p4) {
      const int p = (p4 * 64 + lane) * 4;
      float4 v;
      v.x = (p + 0 >= lo && p + 0 <= hi) ? av_s[wl][p + 0 - c + BAND_] : 0.0f;
      v.y = (p + 1 >= lo && p + 1 <= hi) ? av_s[wl][p + 1 - c + BAND_] : 0.0f;
      v.z = (p + 2 >= lo && p + 2 <= hi) ? av_s[wl][p + 2 - c + BAND_] : 0.0f;
      v.w = (p + 3 >= lo && p + 3 <= hi) ? av_s[wl][p + 3 - c + BAND_] : 0.0f;
      ((float4*)Arow)[p4 * 64 + lane] = v;
    }
    // PV over fixed 33 rows (zero weights for masked)
    float acc[8] = {};
#pragma unroll
    for (int j = 0; j < 33; ++j) {
      const int rcl = min(max(c - BAND_ + j, 0), N_ - 1);
      const float avj = av_s[wl][j];
      const u16x8 v =
          *(const u16x8*)(KV + ((size_t)(b * N_ + rcl)) * 1024 + 512 + lane * 8);
#pragma unroll
      for (int t = 0; t < 8; ++t) acc[t] += avj * bf2f(v[t]);
    }
    u16x8 fo;
#pragma unroll
    for (int t = 0; t < 8; ++t) fo[t] = f2bf(acc[t]);
    *(u16x8*)(Fv + (size_t)(b * L_ + l) * 512 + lane * 8) = fo;
  }
}

// ---------------------------------------------------------------------------
extern "C" void kernel_launch(void* const* d_in, const int* in_sizes, int n_in,
                              void* d_out, int out_size, void* d_ws,
                              size_t ws_size, hipStream_t stream) {
  const float* vis = (const float*)d_in[0];    // [32,1024,512]
  const int* ids = (const int*)d_in[1];        // [32,256,8]
  const float* emb = (const float*)d_in[2];    // [1024,512]
  const float* wq = (const float*)d_in[3];     // [512,512]
  const float* wk = (const float*)d_in[4];     // [512,512]
  const float* wvp = (const float*)d_in[5];    // [512,512]
  const float* wv2t = (const float*)d_in[6];   // [512,512]
  const float* dwk = (const float*)d_in[7];    // [512,1,3]
  const float* pwk = (const float*)d_in[8];    // [512,512,1]
  const float* lng = (const float*)d_in[9];    // [512]
  const float* lnb = (const float*)d_in[10];   // [512]
  const float* alpha = (const float*)d_in[11]; // scalar

  float* out_cls = (float*)d_out;                // [8192,1024]
  float* out_H = out_cls + (size_t)8192 * 1024;  // [8192,512]
  float* out_A = out_H + (size_t)8192 * 512;     // [8192,1024]

  // workspace layout
  char* p = (char*)d_ws;
  u16* visb = (u16*)p;              p += (size_t)32768 * 512 * 2;
  u16* KVb  = (u16*)p;              p += (size_t)32768 * 1024 * 2;
  u16* embb = (u16*)p;              p += (size_t)1024 * 512 * 2;
  u16* wqb  = (u16*)p;              p += (size_t)512 * 512 * 2;
  u16* wkvb = (u16*)p;              p += (size_t)1024 * 512 * 2;
  u16* wv2tb= (u16*)p;              p += (size_t)512 * 512 * 2;
  u16* pwkb = (u16*)p;              p += (size_t)512 * 512 * 2;
  u16* shmb = (u16*)p;              p += (size_t)8192 * 512 * 2;
  float* mbuf = (float*)p;          p += (size_t)8192 * 512 * 4;
  u16* qbuf = (u16*)p;              p += (size_t)8192 * 512 * 2;
  u16* Qbf  = (u16*)p;              p += (size_t)8192 * 512 * 2;
  u16* Fvb  = (u16*)p;              p += (size_t)8192 * 512 * 2;
  u16* Hb   = (u16*)p;              p += (size_t)8192 * 512 * 2;

  // conversions to bf16
  cvt_bf16<<<16384, 256, 0, stream>>>(vis, visb, 32768 * 512 / 4);
  cvt_weights<<<1792, 256, 0, stream>>>(emb, wq, wk, wvp, wv2t, pwk,
                                        embb, wqb, wkvb, wv2tb, pwkb);

  // KV = vis @ [wk;wv]^T  -> bf16 [32768][1024]
  gemm_mfma<false, false, true><<<dim3(8, 256), 256, 0, stream>>>(
      visb, wkvb, nullptr, KVb, 32768, 1024, 512);

  // text front: gather + dwconv + silu + means
  text_front<<<8192, 256, 0, stream>>>(ids, emb, dwk, shmb, mbuf);
  // m += shm_mean @ pw^T  (pointwise conv folded through mean)
  gemm_mfma<true, true, false><<<dim3(4, 64), 256, 0, stream>>>(
      shmb, pwkb, mbuf, nullptr, 8192, 512, 512);
  // LayerNorm -> q_txt (bf16)
  ln_kernel<<<8192, 256, 0, stream>>>(mbuf, lng, lnb, qbuf);
  // Q = q_txt @ wq^T (bf16 out)
  gemm_mfma<false, false, true><<<dim3(4, 64), 256, 0, stream>>>(
      qbuf, wqb, nullptr, Qbf, 8192, 512, 512);
  // banded attention -> A (full rows, f32), Fv (bf16)
  attn_kernel<<<512, 512, 0, stream>>>(Qbf, KVb, alpha, out_A, Fvb);
  // H = Fv @ wv2t^T (f32 out + bf16 copy)
  gemm_mfma<false, true, true><<<dim3(4, 64), 256, 0, stream>>>(
      Fvb, wv2tb, out_H, Hb, 8192, 512, 512);
  // cls = H @ emb^T (f32 out)
  gemm_mfma<false, true, false><<<dim3(8, 64), 256, 0, stream>>>(
      Hb, embb, out_cls, nullptr, 8192, 1024, 512);
}

// Round 6
// 268.381 us; speedup vs baseline: 1.3972x; 1.3972x over previous
//
#include <hip/hip_runtime.h>
#include <cmath>

typedef unsigned short u16;
typedef __attribute__((ext_vector_type(8))) short bf16x8;
typedef __attribute__((ext_vector_type(4))) float f32x4;
typedef __attribute__((ext_vector_type(8))) unsigned short u16x8;

#define B_  32
#define N_  1024
#define L_  256
#define S_  8
#define DT_ 512
#define BAND_ 16

__device__ __forceinline__ u16 f2bf(float f) {
  union { float f; unsigned u; } x; x.f = f;
  unsigned r = (x.u + 0x7fffu + ((x.u >> 16) & 1u)) >> 16;
  return (u16)r;
}
__device__ __forceinline__ float bf2f(u16 h) {
  union { unsigned u; float f; } x; x.u = ((unsigned)h) << 16;
  return x.f;
}

// ---------------------------------------------------------------------------
// f32 -> bf16 conversion (vectorized x4)
// ---------------------------------------------------------------------------
__global__ __launch_bounds__(256) void cvt_bf16(
    const float* __restrict__ in, u16* __restrict__ out, int n4) {
  int i = blockIdx.x * 256 + threadIdx.x;
  if (i < n4) {
    float4 v = ((const float4*)in)[i];
    ushort4 o;
    o.x = f2bf(v.x); o.y = f2bf(v.y); o.z = f2bf(v.z); o.w = f2bf(v.w);
    ((ushort4*)out)[i] = o;
  }
}

// ---------------------------------------------------------------------------
// All small weights in one launch.
// ---------------------------------------------------------------------------
__global__ __launch_bounds__(256) void cvt_weights(
    const float* __restrict__ e, const float* __restrict__ q,
    const float* __restrict__ k, const float* __restrict__ v,
    const float* __restrict__ t, const float* __restrict__ pw,
    u16* __restrict__ eo, u16* __restrict__ qo, u16* __restrict__ kvo,
    u16* __restrict__ to, u16* __restrict__ po) {
  int i = blockIdx.x * 256 + threadIdx.x;
  const float* src; u16* dst; int soff, doff;
  if (i < 131072)      { src = e;  dst = eo;  soff = i;          doff = soff; }
  else if (i < 196608) { src = q;  dst = qo;  soff = i - 131072; doff = soff; }
  else if (i < 262144) { src = k;  dst = kvo; soff = i - 196608; doff = soff; }
  else if (i < 327680) { src = v;  dst = kvo; soff = i - 262144; doff = soff + 65536; }
  else if (i < 393216) { src = t;  dst = to;  soff = i - 327680; doff = soff; }
  else                 { src = pw; dst = po;  soff = i - 393216; doff = soff; }
  float4 vv = ((const float4*)src)[soff];
  ushort4 o;
  o.x = f2bf(vv.x); o.y = f2bf(vv.y); o.z = f2bf(vv.z); o.w = f2bf(vv.w);
  ((ushort4*)dst)[doff] = o;
}

// ---------------------------------------------------------------------------
// K1: per (b,l): gather emb rows, depthwise conv (k=3, SAME, cross-corr),
// silu, mean over s -> shm (bf16); meanE -> mbuf (f32)
// ---------------------------------------------------------------------------
__global__ __launch_bounds__(256) void text_front(
    const int* __restrict__ ids, const float* __restrict__ emb,
    const float* __restrict__ dwk, u16* __restrict__ shm,
    float* __restrict__ mbuf) {
  int bl = blockIdx.x;
  int tid = threadIdx.x;
  __shared__ int sid[S_];
  if (tid < S_) sid[tid] = ids[bl * S_ + tid];
  __syncthreads();
  for (int c = tid; c < DT_; c += 256) {
    float x[S_];
#pragma unroll
    for (int s = 0; s < S_; ++s) x[s] = emb[(size_t)sid[s] * DT_ + c];
    float k0 = dwk[c * 3 + 0], k1 = dwk[c * 3 + 1], k2 = dwk[c * 3 + 2];
    float me = 0.f, sh = 0.f;
#pragma unroll
    for (int s = 0; s < S_; ++s) {
      float xm = (s > 0) ? x[s - 1] : 0.0f;
      float xp = (s < S_ - 1) ? x[s + 1] : 0.0f;
      float h = k0 * xm + k1 * x[s] + k2 * xp;
      float si = h / (1.0f + expf(-h));  // silu
      me += x[s];
      sh += si;
    }
    shm[(size_t)bl * DT_ + c] = f2bf(sh * (1.0f / S_));
    mbuf[(size_t)bl * DT_ + c] = me * (1.0f / S_);
  }
}

// ---------------------------------------------------------------------------
// bf16 MFMA GEMM, 2-phase double-buffered + XCD-chunked swizzle.
// C[m][n] (+)= sum_k A[m][k]*B[n][k]; A:[M,K], B:[N,K] bf16 row-major.
// ---------------------------------------------------------------------------
template <bool ACC, bool WF32, bool WBF16>
__global__ __launch_bounds__(256) void gemm_mfma(
    const u16* __restrict__ A, const u16* __restrict__ B,
    float* __restrict__ C, u16* __restrict__ Cb, int M, int N, int K) {
  __shared__ u16 As[8192];  // [2][128][32]
  __shared__ u16 Bs[8192];
  const int tid = threadIdx.x;
  const int w = tid >> 6;
  const int lane = tid & 63;

  const int gx = gridDim.x;
  const int bid = blockIdx.y * gx + blockIdx.x;
  const int nwg = gx * gridDim.y;
  const int logical = (bid & 7) * (nwg >> 3) + (bid >> 3);
  const int bm = (logical / gx) << 7;
  const int bn = (logical % gx) << 7;
  const int wr = w >> 1, wc = w & 1;

  const int r0 = (w << 4) + (lane >> 2);
  const int kc = (lane & 3) << 3;
  const u16* Ag0 = A + (size_t)(bm + r0) * K + kc;
  const u16* Ag1 = Ag0 + (size_t)64 * K;
  const u16* Bg0 = B + (size_t)(bn + r0) * K + kc;
  const u16* Bg1 = Bg0 + (size_t)64 * K;

  int aoff[4], boff[4];
#pragma unroll
  for (int m = 0; m < 4; ++m)
    aoff[m] = (((wr << 6) + (m << 4) + (lane & 15)) << 5) + ((lane >> 4) << 3);
#pragma unroll
  for (int n = 0; n < 4; ++n)
    boff[n] = (((wc << 6) + (n << 4) + (lane & 15)) << 5) + ((lane >> 4) << 3);

  f32x4 acc[4][4];
#pragma unroll
  for (int m = 0; m < 4; ++m)
#pragma unroll
    for (int n = 0; n < 4; ++n) acc[m][n] = (f32x4){0.f, 0.f, 0.f, 0.f};

#define STAGE(buf, kt)                                                        \
  {                                                                           \
    u16* as_ = As + (buf) * 4096 + (w << 9);                                  \
    u16* bs_ = Bs + (buf) * 4096 + (w << 9);                                  \
    __builtin_amdgcn_global_load_lds(                                         \
        (const __attribute__((address_space(1))) void*)(Ag0 + (kt)),          \
        (__attribute__((address_space(3))) void*)as_, 16, 0, 0);              \
    __builtin_amdgcn_global_load_lds(                                         \
        (const __attribute__((address_space(1))) void*)(Ag1 + (kt)),          \
        (__attribute__((address_space(3))) void*)(as_ + 2048), 16, 0, 0);     \
    __builtin_amdgcn_global_load_lds(                                         \
        (const __attribute__((address_space(1))) void*)(Bg0 + (kt)),          \
        (__attribute__((address_space(3))) void*)bs_, 16, 0, 0);              \
    __builtin_amdgcn_global_load_lds(                                         \
        (const __attribute__((address_space(1))) void*)(Bg1 + (kt)),          \
        (__attribute__((address_space(3))) void*)(bs_ + 2048), 16, 0, 0);     \
  }

  const int nt = K >> 5;
  STAGE(0, 0);
  __syncthreads();
  int cur = 0;
  for (int t = 0; t < nt; ++t) {
    if (t + 1 < nt) STAGE(cur ^ 1, (t + 1) << 5);
    const u16* Ab = As + cur * 4096;
    const u16* Bb = Bs + cur * 4096;
    bf16x8 af[4], bfr[4];
#pragma unroll
    for (int m = 0; m < 4; ++m) af[m] = *(const bf16x8*)(Ab + aoff[m]);
#pragma unroll
    for (int n = 0; n < 4; ++n) bfr[n] = *(const bf16x8*)(Bb + boff[n]);
#pragma unroll
    for (int m = 0; m < 4; ++m)
#pragma unroll
      for (int n = 0; n < 4; ++n)
        acc[m][n] = __builtin_amdgcn_mfma_f32_16x16x32_bf16(
            af[m], bfr[n], acc[m][n], 0, 0, 0);
    __syncthreads();
    cur ^= 1;
  }
#undef STAGE

  const int rb = bm + (wr << 6) + ((lane >> 4) << 2);
  const int cb = bn + (wc << 6) + (lane & 15);
#pragma unroll
  for (int m = 0; m < 4; ++m) {
#pragma unroll
    for (int n = 0; n < 4; ++n) {
      int col = cb + (n << 4);
#pragma unroll
      for (int j = 0; j < 4; ++j) {
        size_t idx = (size_t)(rb + (m << 4) + j) * N + col;
        float v = acc[m][n][j];
        if (ACC) v += C[idx];
        if (WF32) C[idx] = v;
        if (WBF16) Cb[idx] = f2bf(v);
      }
    }
  }
}

// ---------------------------------------------------------------------------
// LayerNorm over DT=512 per row; writes bf16 q_txt
// ---------------------------------------------------------------------------
__global__ __launch_bounds__(256) void ln_kernel(
    const float* __restrict__ m, const float* __restrict__ g,
    const float* __restrict__ bta, u16* __restrict__ q) {
  int row = blockIdx.x;
  int tid = threadIdx.x;
  float v0 = m[(size_t)row * 512 + tid];
  float v1 = m[(size_t)row * 512 + 256 + tid];
  __shared__ float red[4], red2[4];
  float s = v0 + v1;
#pragma unroll
  for (int d = 32; d; d >>= 1) s += __shfl_xor(s, d);
  if ((tid & 63) == 0) red[tid >> 6] = s;
  __syncthreads();
  float mu = (red[0] + red[1] + red[2] + red[3]) * (1.0f / 512.0f);
  float d0 = v0 - mu, d1 = v1 - mu;
  float s2 = d0 * d0 + d1 * d1;
#pragma unroll
  for (int d = 32; d; d >>= 1) s2 += __shfl_xor(s2, d);
  if ((tid & 63) == 0) red2[tid >> 6] = s2;
  __syncthreads();
  float var = (red2[0] + red2[1] + red2[2] + red2[3]) * (1.0f / 512.0f);
  float r = rsqrtf(var + 1e-5f);
  q[(size_t)row * 512 + tid] = f2bf(d0 * r * g[tid] + bta[tid]);
  q[(size_t)row * 512 + 256 + tid] = f2bf(d1 * r * g[tid + 256] + bta[tid + 256]);
}

// ---------------------------------------------------------------------------
// Banded attention. Block = 256 thr = 4 waves; ONE l per wave (grid 2048).
// Fixed 33-iteration clamped band loops, partial unroll 4 (ILP, no spill).
// Q bf16. KV: [32768][1024] bf16, cols 0..511 = K, 512..1023 = V.
// ---------------------------------------------------------------------------
__global__ __launch_bounds__(256) void attn_kernel(
    const u16* __restrict__ Qb, const u16* __restrict__ KV,
    const float* __restrict__ alpha_p, float* __restrict__ A,
    u16* __restrict__ Fv) {
  __shared__ float av_s[4][64];
  // XCD-chunked bijective swizzle over 2048 blocks (256 per XCD)
  const int bid = blockIdx.x;
  const int logical = (bid & 7) * 256 + (bid >> 3);
  const int b = logical >> 6, lq = logical & 63;
  const int w = threadIdx.x >> 6, lane = threadIdx.x & 63;
  const int l = lq * 4 + w;
  const float al = *alpha_p;
  const int c = (1023 * l) / 255;
  const int base = c - BAND_;

  // Q slice into registers (lane owns 8 channels)
  float qr[8];
  {
    const u16x8 qv = *(const u16x8*)(Qb + (size_t)(b * L_ + l) * 512 + lane * 8);
#pragma unroll
    for (int t = 0; t < 8; ++t) qr[t] = bf2f(qv[t]);
  }

  // QK^T over fixed 33 rows (clamped); lane j ends holding logit j
  float mylogit = 0.f;
#pragma unroll 4
  for (int j = 0; j < 33; ++j) {
    const int rcl = min(max(base + j, 0), N_ - 1);
    const u16x8 kv =
        *(const u16x8*)(KV + ((size_t)(b * N_ + rcl)) * 1024 + lane * 8);
    float s = 0.f;
#pragma unroll
    for (int t = 0; t < 8; ++t) s += bf2f(kv[t]) * qr[t];
#pragma unroll
    for (int d = 32; d; d >>= 1) s += __shfl_xor(s, d);
    mylogit = (lane == j) ? s : mylogit;
  }

  // register softmax across lanes (mask invalid rows / lanes >= 33)
  const int myrow = base + lane;
  const bool valid = (lane < 33) && (myrow >= 0) && (myrow < N_);
  float x = valid ? mylogit * 0.044194173824159216f +
                        al * ((float)(c - myrow) * (1.0f / 16.000001f))
                  : -INFINITY;
  float mx = x;
#pragma unroll
  for (int d = 32; d; d >>= 1) mx = fmaxf(mx, __shfl_xor(mx, d));
  float e = valid ? expf(x - mx) : 0.0f;
  float sm = e;
#pragma unroll
  for (int d = 32; d; d >>= 1) sm += __shfl_xor(sm, d);
  av_s[w][lane] = valid ? (e / sm) : 0.0f;

  // A row (float4, zeros outside band)
  const int lo = max(0, base), hi = min(N_ - 1, c + BAND_);
  float* Arow = A + (size_t)(b * L_ + l) * N_;
#pragma unroll
  for (int p4 = 0; p4 < 4; ++p4) {
    const int p = (p4 * 64 + lane) * 4;
    float4 v;
    v.x = (p + 0 >= lo && p + 0 <= hi) ? av_s[w][p + 0 - base] : 0.0f;
    v.y = (p + 1 >= lo && p + 1 <= hi) ? av_s[w][p + 1 - base] : 0.0f;
    v.z = (p + 2 >= lo && p + 2 <= hi) ? av_s[w][p + 2 - base] : 0.0f;
    v.w = (p + 3 >= lo && p + 3 <= hi) ? av_s[w][p + 3 - base] : 0.0f;
    ((float4*)Arow)[p4 * 64 + lane] = v;
  }

  // PV over fixed 33 rows (zero weights for masked)
  float acc[8] = {};
#pragma unroll 4
  for (int j = 0; j < 33; ++j) {
    const int rcl = min(max(base + j, 0), N_ - 1);
    const float avj = av_s[w][j];
    const u16x8 v =
        *(const u16x8*)(KV + ((size_t)(b * N_ + rcl)) * 1024 + 512 + lane * 8);
#pragma unroll
    for (int t = 0; t < 8; ++t) acc[t] += avj * bf2f(v[t]);
  }
  u16x8 fo;
#pragma unroll
  for (int t = 0; t < 8; ++t) fo[t] = f2bf(acc[t]);
  *(u16x8*)(Fv + (size_t)(b * L_ + l) * 512 + lane * 8) = fo;
}

// ---------------------------------------------------------------------------
extern "C" void kernel_launch(void* const* d_in, const int* in_sizes, int n_in,
                              void* d_out, int out_size, void* d_ws,
                              size_t ws_size, hipStream_t stream) {
  const float* vis = (const float*)d_in[0];    // [32,1024,512]
  const int* ids = (const int*)d_in[1];        // [32,256,8]
  const float* emb = (const float*)d_in[2];    // [1024,512]
  const float* wq = (const float*)d_in[3];     // [512,512]
  const float* wk = (const float*)d_in[4];     // [512,512]
  const float* wvp = (const float*)d_in[5];    // [512,512]
  const float* wv2t = (const float*)d_in[6];   // [512,512]
  const float* dwk = (const float*)d_in[7];    // [512,1,3]
  const float* pwk = (const float*)d_in[8];    // [512,512,1]
  const float* lng = (const float*)d_in[9];    // [512]
  const float* lnb = (const float*)d_in[10];   // [512]
  const float* alpha = (const float*)d_in[11]; // scalar

  float* out_cls = (float*)d_out;                // [8192,1024]
  float* out_H = out_cls + (size_t)8192 * 1024;  // [8192,512]
  float* out_A = out_H + (size_t)8192 * 512;     // [8192,1024]

  // workspace layout
  char* p = (char*)d_ws;
  u16* visb = (u16*)p;              p += (size_t)32768 * 512 * 2;
  u16* KVb  = (u16*)p;              p += (size_t)32768 * 1024 * 2;
  u16* embb = (u16*)p;              p += (size_t)1024 * 512 * 2;
  u16* wqb  = (u16*)p;              p += (size_t)512 * 512 * 2;
  u16* wkvb = (u16*)p;              p += (size_t)1024 * 512 * 2;
  u16* wv2tb= (u16*)p;              p += (size_t)512 * 512 * 2;
  u16* pwkb = (u16*)p;              p += (size_t)512 * 512 * 2;
  u16* shmb = (u16*)p;              p += (size_t)8192 * 512 * 2;
  float* mbuf = (float*)p;          p += (size_t)8192 * 512 * 4;
  u16* qbuf = (u16*)p;              p += (size_t)8192 * 512 * 2;
  u16* Qbf  = (u16*)p;              p += (size_t)8192 * 512 * 2;
  u16* Fvb  = (u16*)p;              p += (size_t)8192 * 512 * 2;
  u16* Hb   = (u16*)p;              p += (size_t)8192 * 512 * 2;

  // conversions to bf16
  cvt_bf16<<<16384, 256, 0, stream>>>(vis, visb, 32768 * 512 / 4);
  cvt_weights<<<1792, 256, 0, stream>>>(emb, wq, wk, wvp, wv2t, pwk,
                                        embb, wqb, wkvb, wv2tb, pwkb);

  // KV = vis @ [wk;wv]^T  -> bf16 [32768][1024]
  gemm_mfma<false, false, true><<<dim3(8, 256), 256, 0, stream>>>(
      visb, wkvb, nullptr, KVb, 32768, 1024, 512);

  // text front: gather + dwconv + silu + means
  text_front<<<8192, 256, 0, stream>>>(ids, emb, dwk, shmb, mbuf);
  // m += shm_mean @ pw^T  (pointwise conv folded through mean)
  gemm_mfma<true, true, false><<<dim3(4, 64), 256, 0, stream>>>(
      shmb, pwkb, mbuf, nullptr, 8192, 512, 512);
  // LayerNorm -> q_txt (bf16)
  ln_kernel<<<8192, 256, 0, stream>>>(mbuf, lng, lnb, qbuf);
  // Q = q_txt @ wq^T (bf16 out)
  gemm_mfma<false, false, true><<<dim3(4, 64), 256, 0, stream>>>(
      qbuf, wqb, nullptr, Qbf, 8192, 512, 512);
  // banded attention -> A (full rows, f32), Fv (bf16)
  attn_kernel<<<2048, 256, 0, stream>>>(Qbf, KVb, alpha, out_A, Fvb);
  // H = Fv @ wv2t^T (f32 out + bf16 copy)
  gemm_mfma<false, true, true><<<dim3(4, 64), 256, 0, stream>>>(
      Fvb, wv2tb, out_H, Hb, 8192, 512, 512);
  // cls = H @ emb^T (f32 out)
  gemm_mfma<false, true, false><<<dim3(8, 64), 256, 0, stream>>>(
      Hb, embb, out_cls, nullptr, 8192, 1024, 512);
}

// Round 7
// 219.560 us; speedup vs baseline: 1.7079x; 1.2224x over previous
//
#include <hip/hip_runtime.h>
#include <cmath>

typedef unsigned short u16;
typedef __attribute__((ext_vector_type(8))) short bf16x8;
typedef __attribute__((ext_vector_type(4))) float f32x4;
typedef __attribute__((ext_vector_type(8))) unsigned short u16x8;

#define B_  32
#define N_  1024
#define L_  256
#define S_  8
#define DT_ 512
#define BAND_ 16

__device__ __forceinline__ u16 f2bf(float f) {
  union { float f; unsigned u; } x; x.f = f;
  unsigned r = (x.u + 0x7fffu + ((x.u >> 16) & 1u)) >> 16;
  return (u16)r;
}
__device__ __forceinline__ float bf2f(u16 h) {
  union { unsigned u; float f; } x; x.u = ((unsigned)h) << 16;
  return x.f;
}

// ---------------------------------------------------------------------------
// f32 -> bf16 conversion (vectorized x4)
// ---------------------------------------------------------------------------
__global__ __launch_bounds__(256) void cvt_bf16(
    const float* __restrict__ in, u16* __restrict__ out, int n4) {
  int i = blockIdx.x * 256 + threadIdx.x;
  if (i < n4) {
    float4 v = ((const float4*)in)[i];
    ushort4 o;
    o.x = f2bf(v.x); o.y = f2bf(v.y); o.z = f2bf(v.z); o.w = f2bf(v.w);
    ((ushort4*)out)[i] = o;
  }
}

// ---------------------------------------------------------------------------
// All small weights in one launch.
// ---------------------------------------------------------------------------
__global__ __launch_bounds__(256) void cvt_weights(
    const float* __restrict__ e, const float* __restrict__ q,
    const float* __restrict__ k, const float* __restrict__ v,
    const float* __restrict__ t, const float* __restrict__ pw,
    u16* __restrict__ eo, u16* __restrict__ qo, u16* __restrict__ kvo,
    u16* __restrict__ to, u16* __restrict__ po) {
  int i = blockIdx.x * 256 + threadIdx.x;
  const float* src; u16* dst; int soff, doff;
  if (i < 131072)      { src = e;  dst = eo;  soff = i;          doff = soff; }
  else if (i < 196608) { src = q;  dst = qo;  soff = i - 131072; doff = soff; }
  else if (i < 262144) { src = k;  dst = kvo; soff = i - 196608; doff = soff; }
  else if (i < 327680) { src = v;  dst = kvo; soff = i - 262144; doff = soff + 65536; }
  else if (i < 393216) { src = t;  dst = to;  soff = i - 327680; doff = soff; }
  else                 { src = pw; dst = po;  soff = i - 393216; doff = soff; }
  float4 vv = ((const float4*)src)[soff];
  ushort4 o;
  o.x = f2bf(vv.x); o.y = f2bf(vv.y); o.z = f2bf(vv.z); o.w = f2bf(vv.w);
  ((ushort4*)dst)[doff] = o;
}

// ---------------------------------------------------------------------------
// K1: per (b,l): gather emb rows, depthwise conv (k=3, SAME, cross-corr),
// silu, mean over s -> shm (bf16); meanE -> mbuf (f32)
// ---------------------------------------------------------------------------
__global__ __launch_bounds__(256) void text_front(
    const int* __restrict__ ids, const float* __restrict__ emb,
    const float* __restrict__ dwk, u16* __restrict__ shm,
    float* __restrict__ mbuf) {
  int bl = blockIdx.x;
  int tid = threadIdx.x;
  __shared__ int sid[S_];
  if (tid < S_) sid[tid] = ids[bl * S_ + tid];
  __syncthreads();
  for (int c = tid; c < DT_; c += 256) {
    float x[S_];
#pragma unroll
    for (int s = 0; s < S_; ++s) x[s] = emb[(size_t)sid[s] * DT_ + c];
    float k0 = dwk[c * 3 + 0], k1 = dwk[c * 3 + 1], k2 = dwk[c * 3 + 2];
    float me = 0.f, sh = 0.f;
#pragma unroll
    for (int s = 0; s < S_; ++s) {
      float xm = (s > 0) ? x[s - 1] : 0.0f;
      float xp = (s < S_ - 1) ? x[s + 1] : 0.0f;
      float h = k0 * xm + k1 * x[s] + k2 * xp;
      float si = h / (1.0f + expf(-h));  // silu
      me += x[s];
      sh += si;
    }
    shm[(size_t)bl * DT_ + c] = f2bf(sh * (1.0f / S_));
    mbuf[(size_t)bl * DT_ + c] = me * (1.0f / S_);
  }
}

// ---------------------------------------------------------------------------
// bf16 MFMA GEMM, 2-phase double-buffered + XCD-chunked swizzle.
// C[m][n] (+)= sum_k A[m][k]*B[n][k]; A:[M,K], B:[N,K] bf16 row-major.
// ---------------------------------------------------------------------------
template <bool ACC, bool WF32, bool WBF16>
__global__ __launch_bounds__(256) void gemm_mfma(
    const u16* __restrict__ A, const u16* __restrict__ B,
    float* __restrict__ C, u16* __restrict__ Cb, int M, int N, int K) {
  __shared__ u16 As[8192];  // [2][128][32]
  __shared__ u16 Bs[8192];
  const int tid = threadIdx.x;
  const int w = tid >> 6;
  const int lane = tid & 63;

  const int gx = gridDim.x;
  const int bid = blockIdx.y * gx + blockIdx.x;
  const int nwg = gx * gridDim.y;
  const int logical = (bid & 7) * (nwg >> 3) + (bid >> 3);
  const int bm = (logical / gx) << 7;
  const int bn = (logical % gx) << 7;
  const int wr = w >> 1, wc = w & 1;

  const int r0 = (w << 4) + (lane >> 2);
  const int kc = (lane & 3) << 3;
  const u16* Ag0 = A + (size_t)(bm + r0) * K + kc;
  const u16* Ag1 = Ag0 + (size_t)64 * K;
  const u16* Bg0 = B + (size_t)(bn + r0) * K + kc;
  const u16* Bg1 = Bg0 + (size_t)64 * K;

  int aoff[4], boff[4];
#pragma unroll
  for (int m = 0; m < 4; ++m)
    aoff[m] = (((wr << 6) + (m << 4) + (lane & 15)) << 5) + ((lane >> 4) << 3);
#pragma unroll
  for (int n = 0; n < 4; ++n)
    boff[n] = (((wc << 6) + (n << 4) + (lane & 15)) << 5) + ((lane >> 4) << 3);

  f32x4 acc[4][4];
#pragma unroll
  for (int m = 0; m < 4; ++m)
#pragma unroll
    for (int n = 0; n < 4; ++n) acc[m][n] = (f32x4){0.f, 0.f, 0.f, 0.f};

#define STAGE(buf, kt)                                                        \
  {                                                                           \
    u16* as_ = As + (buf) * 4096 + (w << 9);                                  \
    u16* bs_ = Bs + (buf) * 4096 + (w << 9);                                  \
    __builtin_amdgcn_global_load_lds(                                         \
        (const __attribute__((address_space(1))) void*)(Ag0 + (kt)),          \
        (__attribute__((address_space(3))) void*)as_, 16, 0, 0);              \
    __builtin_amdgcn_global_load_lds(                                         \
        (const __attribute__((address_space(1))) void*)(Ag1 + (kt)),          \
        (__attribute__((address_space(3))) void*)(as_ + 2048), 16, 0, 0);     \
    __builtin_amdgcn_global_load_lds(                                         \
        (const __attribute__((address_space(1))) void*)(Bg0 + (kt)),          \
        (__attribute__((address_space(3))) void*)bs_, 16, 0, 0);              \
    __builtin_amdgcn_global_load_lds(                                         \
        (const __attribute__((address_space(1))) void*)(Bg1 + (kt)),          \
        (__attribute__((address_space(3))) void*)(bs_ + 2048), 16, 0, 0);     \
  }

  const int nt = K >> 5;
  STAGE(0, 0);
  __syncthreads();
  int cur = 0;
  for (int t = 0; t < nt; ++t) {
    if (t + 1 < nt) STAGE(cur ^ 1, (t + 1) << 5);
    const u16* Ab = As + cur * 4096;
    const u16* Bb = Bs + cur * 4096;
    bf16x8 af[4], bfr[4];
#pragma unroll
    for (int m = 0; m < 4; ++m) af[m] = *(const bf16x8*)(Ab + aoff[m]);
#pragma unroll
    for (int n = 0; n < 4; ++n) bfr[n] = *(const bf16x8*)(Bb + boff[n]);
#pragma unroll
    for (int m = 0; m < 4; ++m)
#pragma unroll
      for (int n = 0; n < 4; ++n)
        acc[m][n] = __builtin_amdgcn_mfma_f32_16x16x32_bf16(
            af[m], bfr[n], acc[m][n], 0, 0, 0);
    __syncthreads();
    cur ^= 1;
  }
#undef STAGE

  const int rb = bm + (wr << 6) + ((lane >> 4) << 2);
  const int cb = bn + (wc << 6) + (lane & 15);
#pragma unroll
  for (int m = 0; m < 4; ++m) {
#pragma unroll
    for (int n = 0; n < 4; ++n) {
      int col = cb + (n << 4);
#pragma unroll
      for (int j = 0; j < 4; ++j) {
        size_t idx = (size_t)(rb + (m << 4) + j) * N + col;
        float v = acc[m][n][j];
        if (ACC) v += C[idx];
        if (WF32) C[idx] = v;
        if (WBF16) Cb[idx] = f2bf(v);
      }
    }
  }
}

// ---------------------------------------------------------------------------
// LayerNorm over DT=512 per row; writes bf16 q_txt
// ---------------------------------------------------------------------------
__global__ __launch_bounds__(256) void ln_kernel(
    const float* __restrict__ m, const float* __restrict__ g,
    const float* __restrict__ bta, u16* __restrict__ q) {
  int row = blockIdx.x;
  int tid = threadIdx.x;
  float v0 = m[(size_t)row * 512 + tid];
  float v1 = m[(size_t)row * 512 + 256 + tid];
  __shared__ float red[4], red2[4];
  float s = v0 + v1;
#pragma unroll
  for (int d = 32; d; d >>= 1) s += __shfl_xor(s, d);
  if ((tid & 63) == 0) red[tid >> 6] = s;
  __syncthreads();
  float mu = (red[0] + red[1] + red[2] + red[3]) * (1.0f / 512.0f);
  float d0 = v0 - mu, d1 = v1 - mu;
  float s2 = d0 * d0 + d1 * d1;
#pragma unroll
  for (int d = 32; d; d >>= 1) s2 += __shfl_xor(s2, d);
  if ((tid & 63) == 0) red2[tid >> 6] = s2;
  __syncthreads();
  float var = (red2[0] + red2[1] + red2[2] + red2[3]) * (1.0f / 512.0f);
  float r = rsqrtf(var + 1e-5f);
  q[(size_t)row * 512 + tid] = f2bf(d0 * r * g[tid] + bta[tid]);
  q[(size_t)row * 512 + 256 + tid] = f2bf(d1 * r * g[tid + 256] + bta[tid + 256]);
}

// ---------------------------------------------------------------------------
// MFMA banded attention. Block = (b, 16 l), 512 threads = 8 waves.
// Key band: 96 keys starting at kb0 (covers all 16 bands, span <= 94).
// Phase 1: stage K band (96x512 bf16, XOR-swizzled src -> linear LDS) + Q.
// Phase 2: QK^T via mfma 16x16x32 (waves 0..5, one 16-key tile each) -> S_lds.
// Phase 3: issue V stage (same LDS buffer); softmax + A-row write overlaps.
// Phase 4: PV from V_lds (runtime band loop, LDS-latency only) -> Fv.
// ---------------------------------------------------------------------------
__global__ __launch_bounds__(512) void attn_kernel(
    const u16* __restrict__ Qb, const u16* __restrict__ KV,
    const float* __restrict__ alpha_p, float* __restrict__ A,
    u16* __restrict__ Fv) {
  __shared__ u16 KV_s[96 * 512];   // 96 KB, K then reused for V
  __shared__ u16 Q_s[16 * 520];    // padded stride 520 u16
  __shared__ float S_s[16 * 100];  // logits then attention weights

  // XCD-chunked swizzle: 512 blocks, 64 per XCD (4 batches' KV per XCD L2)
  const int bid = blockIdx.x;
  const int logical = (bid & 7) * 64 + (bid >> 3);
  const int b = logical >> 4, lg = logical & 15;
  const int l0 = lg * 16;
  const int tid = threadIdx.x;
  const int w = tid >> 6, lane = tid & 63;
  const float al = *alpha_p;

  const int c_min = (1023 * l0) / 255;
  const int kb0 = min(max(c_min - BAND_, 0), N_ - 96);

  // ---- stage K band: wave w stages rows w*12 .. w*12+11 ----
  {
    const size_t rowb = (size_t)(b * N_ + kb0);
    for (int rr = 0; rr < 12; ++rr) {
      const int r = w * 12 + rr;
      const u16* src = KV + (rowb + r) * 1024 + ((lane * 8) ^ ((r & 7) << 3));
      u16* dst = KV_s + r * 512;
      __builtin_amdgcn_global_load_lds(
          (const __attribute__((address_space(1))) void*)src,
          (__attribute__((address_space(3))) void*)dst, 16, 0, 0);
    }
  }
  // ---- stage Q tile [16][512] into padded LDS ----
  {
    const int r = tid >> 5;
    const u16* qrow = Qb + (size_t)(b * L_ + l0 + r) * 512;
#pragma unroll
    for (int h = 0; h < 2; ++h) {
      const int ch = (tid & 31) + h * 32;
      u16x8 v = *(const u16x8*)(qrow + ch * 8);
      *(u16x8*)(Q_s + r * 520 + ch * 8) = v;
    }
  }
  __syncthreads();  // K + Q staged (vmcnt drained)

  // ---- QK^T: wave w (<6) computes S[16][16 keys at kb0 + w*16] ----
  if (w < 6) {
    f32x4 acc = {0.f, 0.f, 0.f, 0.f};
    const int arow = (lane & 15) * 520 + ((lane >> 4) << 3);
    const int key = w * 16 + (lane & 15);
    const int swz = (key & 7) << 3;
    for (int ks = 0; ks < 16; ++ks) {
      bf16x8 aq = *(const bf16x8*)(Q_s + arow + ks * 32);
      bf16x8 bk =
          *(const bf16x8*)(KV_s + key * 512 + ((ks * 32 + ((lane >> 4) << 3)) ^ swz));
      acc = __builtin_amdgcn_mfma_f32_16x16x32_bf16(aq, bk, acc, 0, 0, 0);
    }
#pragma unroll
    for (int j = 0; j < 4; ++j)
      S_s[((lane >> 4) * 4 + j) * 100 + w * 16 + (lane & 15)] = acc[j];
  }
  __syncthreads();  // S complete; all K reads done

  // ---- issue V stage (overwrites KV_s); latency hides under softmax ----
  {
    const size_t rowb = (size_t)(b * N_ + kb0);
    for (int rr = 0; rr < 12; ++rr) {
      const int r = w * 12 + rr;
      const u16* src =
          KV + (rowb + r) * 1024 + 512 + ((lane * 8) ^ ((r & 7) << 3));
      u16* dst = KV_s + r * 512;
      __builtin_amdgcn_global_load_lds(
          (const __attribute__((address_space(1))) void*)src,
          (__attribute__((address_space(3))) void*)dst, 16, 0, 0);
    }
  }

  // ---- softmax + A-row write: wave w owns rows 2w, 2w+1 ----
#pragma unroll
  for (int rr = 0; rr < 2; ++rr) {
    const int l = 2 * w + rr;
    const int c = (1023 * (l0 + l)) / 255;
    const int g0 = kb0 + lane, g1 = kb0 + 64 + lane;
    const bool v0 = (g0 >= c - BAND_) && (g0 <= c + BAND_);
    const bool v1 = (lane < 32) && (g1 >= c - BAND_) && (g1 <= c + BAND_);
    const float sc = 0.044194173824159216f;
    float x0 = v0 ? S_s[l * 100 + lane] * sc +
                        al * ((float)(c - g0) * (1.0f / 16.000001f))
                  : -INFINITY;
    float x1 = v1 ? S_s[l * 100 + 64 + lane] * sc +
                        al * ((float)(c - g1) * (1.0f / 16.000001f))
                  : -INFINITY;
    float mx = fmaxf(x0, x1);
#pragma unroll
    for (int d = 32; d; d >>= 1) mx = fmaxf(mx, __shfl_xor(mx, d));
    float e0 = v0 ? expf(x0 - mx) : 0.0f;
    float e1 = v1 ? expf(x1 - mx) : 0.0f;
    float sm = e0 + e1;
#pragma unroll
    for (int d = 32; d; d >>= 1) sm += __shfl_xor(sm, d);
    const float inv = 1.0f / sm;
    S_s[l * 100 + lane] = e0 * inv;
    if (lane < 32) S_s[l * 100 + 64 + lane] = e1 * inv;
    // A row (float4, zeros outside band)
    const int lo = max(0, c - BAND_), hi = min(N_ - 1, c + BAND_);
    float* Arow = A + (size_t)(b * L_ + l0 + l) * N_;
#pragma unroll
    for (int p4 = 0; p4 < 4; ++p4) {
      const int p = (p4 * 64 + lane) * 4;
      float4 v;
      v.x = (p + 0 >= lo && p + 0 <= hi) ? S_s[l * 100 + p + 0 - kb0] : 0.0f;
      v.y = (p + 1 >= lo && p + 1 <= hi) ? S_s[l * 100 + p + 1 - kb0] : 0.0f;
      v.z = (p + 2 >= lo && p + 2 <= hi) ? S_s[l * 100 + p + 2 - kb0] : 0.0f;
      v.w = (p + 3 >= lo && p + 3 <= hi) ? S_s[l * 100 + p + 3 - kb0] : 0.0f;
      ((float4*)Arow)[p4 * 64 + lane] = v;
    }
  }
  __syncthreads();  // V staged (vmcnt drained), av final

  // ---- PV: wave w owns rows 2w, 2w+1; lane owns 8 V channels ----
#pragma unroll
  for (int rr = 0; rr < 2; ++rr) {
    const int l = 2 * w + rr;
    const int c = (1023 * (l0 + l)) / 255;
    const int jlo = max(0, c - BAND_) - kb0, jhi = min(N_ - 1, c + BAND_) - kb0;
    float acc[8] = {};
    for (int j = jlo; j <= jhi; ++j) {
      const float avj = S_s[l * 100 + j];
      const u16x8 v =
          *(const u16x8*)(KV_s + j * 512 + ((lane * 8) ^ ((j & 7) << 3)));
#pragma unroll
      for (int t = 0; t < 8; ++t) acc[t] += avj * bf2f(v[t]);
    }
    u16x8 fo;
#pragma unroll
    for (int t = 0; t < 8; ++t) fo[t] = f2bf(acc[t]);
    *(u16x8*)(Fv + (size_t)(b * L_ + l0 + l) * 512 + lane * 8) = fo;
  }
}

// ---------------------------------------------------------------------------
extern "C" void kernel_launch(void* const* d_in, const int* in_sizes, int n_in,
                              void* d_out, int out_size, void* d_ws,
                              size_t ws_size, hipStream_t stream) {
  const float* vis = (const float*)d_in[0];    // [32,1024,512]
  const int* ids = (const int*)d_in[1];        // [32,256,8]
  const float* emb = (const float*)d_in[2];    // [1024,512]
  const float* wq = (const float*)d_in[3];     // [512,512]
  const float* wk = (const float*)d_in[4];     // [512,512]
  const float* wvp = (const float*)d_in[5];    // [512,512]
  const float* wv2t = (const float*)d_in[6];   // [512,512]
  const float* dwk = (const float*)d_in[7];    // [512,1,3]
  const float* pwk = (const float*)d_in[8];    // [512,512,1]
  const float* lng = (const float*)d_in[9];    // [512]
  const float* lnb = (const float*)d_in[10];   // [512]
  const float* alpha = (const float*)d_in[11]; // scalar

  float* out_cls = (float*)d_out;                // [8192,1024]
  float* out_H = out_cls + (size_t)8192 * 1024;  // [8192,512]
  float* out_A = out_H + (size_t)8192 * 512;     // [8192,1024]

  // workspace layout
  char* p = (char*)d_ws;
  u16* visb = (u16*)p;              p += (size_t)32768 * 512 * 2;
  u16* KVb  = (u16*)p;              p += (size_t)32768 * 1024 * 2;
  u16* embb = (u16*)p;              p += (size_t)1024 * 512 * 2;
  u16* wqb  = (u16*)p;              p += (size_t)512 * 512 * 2;
  u16* wkvb = (u16*)p;              p += (size_t)1024 * 512 * 2;
  u16* wv2tb= (u16*)p;              p += (size_t)512 * 512 * 2;
  u16* pwkb = (u16*)p;              p += (size_t)512 * 512 * 2;
  u16* shmb = (u16*)p;              p += (size_t)8192 * 512 * 2;
  float* mbuf = (float*)p;          p += (size_t)8192 * 512 * 4;
  u16* qbuf = (u16*)p;              p += (size_t)8192 * 512 * 2;
  u16* Qbf  = (u16*)p;              p += (size_t)8192 * 512 * 2;
  u16* Fvb  = (u16*)p;              p += (size_t)8192 * 512 * 2;
  u16* Hb   = (u16*)p;              p += (size_t)8192 * 512 * 2;

  // conversions to bf16
  cvt_bf16<<<16384, 256, 0, stream>>>(vis, visb, 32768 * 512 / 4);
  cvt_weights<<<1792, 256, 0, stream>>>(emb, wq, wk, wvp, wv2t, pwk,
                                        embb, wqb, wkvb, wv2tb, pwkb);

  // KV = vis @ [wk;wv]^T  -> bf16 [32768][1024]
  gemm_mfma<false, false, true><<<dim3(8, 256), 256, 0, stream>>>(
      visb, wkvb, nullptr, KVb, 32768, 1024, 512);

  // text front: gather + dwconv + silu + means
  text_front<<<8192, 256, 0, stream>>>(ids, emb, dwk, shmb, mbuf);
  // m += shm_mean @ pw^T  (pointwise conv folded through mean)
  gemm_mfma<true, true, false><<<dim3(4, 64), 256, 0, stream>>>(
      shmb, pwkb, mbuf, nullptr, 8192, 512, 512);
  // LayerNorm -> q_txt (bf16)
  ln_kernel<<<8192, 256, 0, stream>>>(mbuf, lng, lnb, qbuf);
  // Q = q_txt @ wq^T (bf16 out)
  gemm_mfma<false, false, true><<<dim3(4, 64), 256, 0, stream>>>(
      qbuf, wqb, nullptr, Qbf, 8192, 512, 512);
  // banded attention (MFMA) -> A (full rows, f32), Fv (bf16)
  attn_kernel<<<512, 512, 0, stream>>>(Qbf, KVb, alpha, out_A, Fvb);
  // H = Fv @ wv2t^T (f32 out + bf16 copy)
  gemm_mfma<false, true, true><<<dim3(4, 64), 256, 0, stream>>>(
      Fvb, wv2tb, out_H, Hb, 8192, 512, 512);
  // cls = H @ emb^T (f32 out)
  gemm_mfma<false, true, false><<<dim3(8, 64), 256, 0, stream>>>(
      Hb, embb, out_cls, nullptr, 8192, 1024, 512);
}